// Round 11
// baseline (154.850 us; speedup 1.0000x reference)
//
#include <hip/hip_runtime.h>

// ---- static config (matches reference) ----
constexpr int kNImgs   = 9;
constexpr int kC       = 24;
constexpr int kHF      = 112, kWF = 112;
constexpr int kHD      = 56,  kWD = 56;
constexpr int kNPix    = kHD * kWD;              // 3136
constexpr int kNPlanes = 64;
constexpr int kPtsPerRef = kNPlanes * kNPix;     // 200704
constexpr int kEdgesPerRef = 8;
constexpr int kNEdges  = kNImgs * kEdgesPerRef;  // 72
constexpr int kFeatPix = kHF * kWF;              // 12544
constexpr int kFeatPerImg = kC * kFeatPix;       // 301056

// block geometry: 256 threads = 32 d (lane-major) x 8 p
constexpr int kDTile = 32, kPTile = 8;
constexpr int kDHalves = kNPlanes / kDTile;        // 2
constexpr int kPGroups = kNPix / kPTile;           // 392
constexpr int kBlocksPerRef = kDHalves * kPGroups; // 784

typedef _Float16 half8  __attribute__((ext_vector_type(8)));
typedef _Float16 half2v __attribute__((ext_vector_type(2)));
typedef float    float2v __attribute__((ext_vector_type(2)));
typedef unsigned int uint4v __attribute__((ext_vector_type(4)));

__device__ inline half2v u2h(unsigned int u) {
  union { unsigned int u; half2v h; } cv; cv.u = u; return cv.h;
}

#if __has_builtin(__builtin_amdgcn_rcpf)
__device__ inline float fastrcp(float x) { return __builtin_amdgcn_rcpf(x); }
#else
__device__ inline float fastrcp(float x) { return 1.0f / x; }
#endif

// ---------- small 3x3 helpers ----------
__device__ inline void mm3(const float* A, const float* B, float* C) {
#pragma unroll
  for (int i = 0; i < 3; ++i)
#pragma unroll
    for (int j = 0; j < 3; ++j)
      C[i*3+j] = A[i*3+0]*B[0*3+j] + A[i*3+1]*B[1*3+j] + A[i*3+2]*B[2*3+j];
}

__device__ inline void inv3(const float* A, float* I) {
  float a=A[0],b=A[1],c=A[2],d=A[3],e=A[4],f=A[5],g=A[6],h=A[7],i=A[8];
  float c00 = e*i - f*h;
  float c01 = -(d*i - f*g);
  float c02 = d*h - e*g;
  float det = a*c00 + b*c01 + c*c02;
  float r = 1.0f / det;
  I[0] = c00*r;           I[1] = (c*h - b*i)*r;  I[2] = (b*f - c*e)*r;
  I[3] = c01*r;           I[4] = (a*i - c*g)*r;  I[5] = (c*d - a*f)*r;
  I[6] = c02*r;           I[7] = (b*g - a*h)*r;  I[8] = (a*e - b*d)*r;
}

// ---------- transpose+convert feats [N,C,HF,WF] f32 -> [N,HF,WF,C] f16 ----------
__global__ __launch_bounds__(256)
void transpose_feats_kernel(const float* __restrict__ f, _Float16* __restrict__ ft) {
  int idx = blockIdx.x * 256 + threadIdx.x;
  if (idx >= kNImgs * kFeatPerImg) return;
  int n  = idx / kFeatPerImg;
  int r  = idx - n * kFeatPerImg;
  int c  = r / kFeatPix;
  int yx = r - c * kFeatPix;
  ft[((size_t)n * kFeatPix + yx) * kC + c] = (_Float16)f[idx];
}

// ---------- main fused kernel ----------
// block = (ref n, d-half, p-group); lanes d-major (wave = 32 d x 2 p) so a
// wave's gathers walk an epipolar segment (sub-pixel step -> line sharing).
// Inner loop: v_pk_fma_f16 over natural channel pairs, f32 edge accumulation,
// unroll-2 over edges for ILP. VGPR must stay <= 64 (R9 cliff lesson); no
// manual pipeline (R8 spill lesson).
template <bool TR>
__global__ __launch_bounds__(256)
void psv_var_kernel(const float* __restrict__ feats,      // [N,C,HF,WF] f32 (!TR)
                    const _Float16* __restrict__ featsT,  // [N,HF,WF,C] f16 (TR)
                    const float* __restrict__ rotmats,    // [N,3,3]
                    const float* __restrict__ tvecs,      // [N,3]
                    const float* __restrict__ Kmat,       // [N,3,3]
                    const int*   __restrict__ edges,      // [2,72]
                    float* __restrict__ out) {            // [N,C,D,HD,WD]
  __shared__ float sM[kEdgesPerRef][9];
  __shared__ float sB[kEdgesPerRef][3];
  __shared__ int   sSrc[kEdgesPerRef];
  __shared__ int   sUIdx[kEdgesPerRef];
  __shared__ float sMult[kEdgesPerRef];
  __shared__ int   sKU;
  // stride 36: write bank=(4*psub+dsub)%32, read bank=(4*pp2+dd2)%32 —
  // both <=2 lanes/bank (free). 12x8x36x4 = 13,824 B.
  __shared__ float sT[kC / 2][kPTile][kDTile + 4];

  // bijective XCD-chunk swizzle (m204 formula; works for any gridDim)
  const int nwg = gridDim.x;
  const int orig = blockIdx.x;
  const int q = nwg >> 3, r8 = nwg & 7;
  const int xcd = orig & 7, lin = orig >> 3;
  const int bid = ((xcd < r8) ? xcd * (q + 1) : r8 * (q + 1) + (xcd - r8) * q) + lin;

  const int n     = bid / kBlocksPerRef;
  const int rem   = bid - n * kBlocksPerRef;
  const int dHalf = rem / kPGroups;
  const int pG    = rem - dHalf * kPGroups;

  const int t = threadIdx.x;

  if (t < kEdgesPerRef) {
    const int e  = n * kEdgesPerRef + t;
    const int re = edges[e];            // ref row
    const int se = edges[kNEdges + e];  // src row
    sSrc[t] = se;

    const float* Rr = rotmats + re * 9;
    const float* Rs = rotmats + se * 9;
    const float* Kr = Kmat + re * 9;
    const float* Ks = Kmat + se * 9;
    const float* tr = tvecs + re * 3;
    const float* ts = tvecs + se * 3;

    float RrT[9];
#pragma unroll
    for (int i = 0; i < 3; ++i)
#pragma unroll
      for (int j = 0; j < 3; ++j) RrT[i*3+j] = Rr[j*3+i];

    float Kinv[9], A[9], T1[9], M[9];
    inv3(Kr, Kinv);
    mm3(Rs, RrT, A);       // A = R_src * R_ref^T
    mm3(A, Kinv, T1);
    mm3(Ks, T1, M);        // M = K_src * A * K_ref^-1

    float At0 = A[0]*tr[0] + A[1]*tr[1] + A[2]*tr[2];
    float At1 = A[3]*tr[0] + A[4]*tr[1] + A[5]*tr[2];
    float At2 = A[6]*tr[0] + A[7]*tr[1] + A[8]*tr[2];
    float bv0 = ts[0] - At0, bv1 = ts[1] - At1, bv2 = ts[2] - At2;
#pragma unroll
    for (int i = 0; i < 9; ++i) sM[t][i] = M[i];
#pragma unroll
    for (int i = 0; i < 3; ++i)
      sB[t][i] = Ks[i*3+0]*bv0 + Ks[i*3+1]*bv1 + Ks[i*3+2]*bv2;
  }
  __syncthreads();

  if (t == 0) {
    int k = 0;
    for (int j = 0; j < kEdgesPerRef; ++j) {
      const int s = sSrc[j];
      bool dup = false;
      for (int i = 0; i < k; ++i) {
        if (sSrc[sUIdx[i]] == s) { sMult[i] += 1.0f; dup = true; break; }
      }
      if (!dup) { sUIdx[k] = j; sMult[k] = 1.0f; ++k; }
    }
    sKU = k;
  }
  __syncthreads();

  // d-major lane mapping
  const int dsub = t & 31;
  const int psub = t >> 5;
  const int d = dHalf * kDTile + dsub;
  const int p = pG * kPTile + psub;
  const int h = p / kWD;
  const int w = p - h * kWD;

  const float u = (float)w * (447.0f / 55.0f);   // linspace(0,447,56)
  const float v = (float)h * (447.0f / 55.0f);
  const float depth = 0.5f + 0.05f * (float)d;

  float2v acc2[kC / 2], accsq2[kC / 2];
#pragma unroll
  for (int i = 0; i < kC / 2; ++i) {
    acc2[i] = (float2v){0.0f, 0.0f};
    accsq2[i] = (float2v){0.0f, 0.0f};
  }

  const int kU = sKU;

#pragma unroll 2
  for (int jj = 0; jj < kU; ++jj) {
    const int j = sUIdx[jj];
    const float mult = sMult[jj];
    const float* M = sM[j];
    const float px = depth * (M[0]*u + M[1]*v + M[2]) + sB[j][0];
    const float py = depth * (M[3]*u + M[4]*v + M[5]) + sB[j][1];
    const float pz = depth * (M[6]*u + M[7]*v + M[8]) + sB[j][2];
    const float rz = fastrcp(fabsf(pz) + 1e-8f);

    const float x = px * rz * (111.0f / 447.0f);
    const float y = py * rz * (111.0f / 447.0f);

    const float x0 = floorf(x), y0 = floorf(y);
    const float wx = x - x0, wy = y - y0;
    const bool vx0 = (x0 >= 0.0f)  && (x0 <= 111.0f);
    const bool vx1 = (x0 >= -1.0f) && (x0 <= 110.0f);
    const bool vy0 = (y0 >= 0.0f)  && (y0 <= 111.0f);
    const bool vy1 = (y0 >= -1.0f) && (y0 <= 110.0f);
    const float w00 = (vx0 && vy0) ? (1.0f - wx) * (1.0f - wy) : 0.0f;
    const float w01 = (vx1 && vy0) ? wx * (1.0f - wy) : 0.0f;
    const float w10 = (vx0 && vy1) ? (1.0f - wx) * wy : 0.0f;
    const float w11 = (vx1 && vy1) ? wx * wy : 0.0f;

    const int xc0 = (int)fminf(fmaxf(x0,        0.0f), 111.0f);
    const int xc1 = (int)fminf(fmaxf(x0 + 1.0f, 0.0f), 111.0f);
    const int yc0 = (int)fminf(fmaxf(y0,        0.0f), 111.0f);
    const int yc1 = (int)fminf(fmaxf(y0 + 1.0f, 0.0f), 111.0f);

    const int src = sSrc[j];
    if constexpr (TR) {
      const _Float16 h00 = (_Float16)w00, h01 = (_Float16)w01;
      const _Float16 h10 = (_Float16)w10, h11 = (_Float16)w11;
      const half2v w00p = {h00, h00}, w01p = {h01, h01};
      const half2v w10p = {h10, h10}, w11p = {h11, h11};
      const _Float16* base = featsT + (size_t)src * kFeatPix * kC;
      const int o00 = (yc0 * kWF + xc0) * kC;
      const int o01 = (yc0 * kWF + xc1) * kC;
      const int o10 = (yc1 * kWF + xc0) * kC;
      const int o11 = (yc1 * kWF + xc1) * kC;
      const bool m1 = (mult == 1.0f);   // block-uniform branch
      if (m1) {
#pragma unroll
        for (int i = 0; i < kC / 8; ++i) {
          const uint4v q00 = *(const uint4v*)(base + o00 + 8*i);
          const uint4v q01 = *(const uint4v*)(base + o01 + 8*i);
          const uint4v q10 = *(const uint4v*)(base + o10 + 8*i);
          const uint4v q11 = *(const uint4v*)(base + o11 + 8*i);
#pragma unroll
          for (int k2 = 0; k2 < 4; ++k2) {
            const half2v val2h = u2h(q00[k2]) * w00p + u2h(q01[k2]) * w01p
                               + u2h(q10[k2]) * w10p + u2h(q11[k2]) * w11p;
            const float2v val2 = {(float)val2h[0], (float)val2h[1]};
            const int idx = i*4 + k2;
            acc2[idx] += val2;
            accsq2[idx] = val2 * val2 + accsq2[idx];
          }
        }
      } else {
        const float2v mult2 = {mult, mult};
#pragma unroll
        for (int i = 0; i < kC / 8; ++i) {
          const uint4v q00 = *(const uint4v*)(base + o00 + 8*i);
          const uint4v q01 = *(const uint4v*)(base + o01 + 8*i);
          const uint4v q10 = *(const uint4v*)(base + o10 + 8*i);
          const uint4v q11 = *(const uint4v*)(base + o11 + 8*i);
#pragma unroll
          for (int k2 = 0; k2 < 4; ++k2) {
            const half2v val2h = u2h(q00[k2]) * w00p + u2h(q01[k2]) * w01p
                               + u2h(q10[k2]) * w10p + u2h(q11[k2]) * w11p;
            const float2v val2 = {(float)val2h[0], (float)val2h[1]};
            const float2v s2 = val2 * val2;
            const int idx = i*4 + k2;
            acc2[idx] = mult2 * val2 + acc2[idx];
            accsq2[idx] = mult2 * s2 + accsq2[idx];
          }
        }
      }
    } else {
      const float* base = feats + (size_t)src * kFeatPerImg;
      const int o00 = yc0 * kWF + xc0;
      const int o01 = yc0 * kWF + xc1;
      const int o10 = yc1 * kWF + xc0;
      const int o11 = yc1 * kWF + xc1;
#pragma unroll
      for (int i = 0; i < kC / 2; ++i) {
#pragma unroll
        for (int kk = 0; kk < 2; ++kk) {
          const int c = 2*i + kk;
          const float* bc = base + (size_t)c * kFeatPix;
          float val = w00*bc[o00] + w01*bc[o01] + w10*bc[o10] + w11*bc[o11];
          const float mval = mult * val;
          acc2[i][kk] += mval;
          accsq2[i][kk] = __builtin_fmaf(mval, val, accsq2[i][kk]);
        }
      }
    }
  }

  // ---- epilogue: LDS transpose (d-major lanes -> p-coalesced stores) ----
  // two phases of 12 channels; 2 barriers each.
  const int pp2 = t & (kPTile - 1);   // store-side pixel index (0..7)
  const int dd2 = t >> 3;             // store-side depth index (0..31)
  const size_t outBase = (size_t)n * kC * (size_t)kPtsPerRef;
#pragma unroll
  for (int ph = 0; ph < 2; ++ph) {
    __syncthreads();               // protect previous phase's reads
#pragma unroll
    for (int cc = 0; cc < kC / 2; ++cc) {
      const int c = ph * (kC / 2) + cc;
      const float a = acc2[c >> 1][c & 1];
      const float s = accsq2[c >> 1][c & 1];
      const float mean = a * 0.125f;
      sT[cc][psub][dsub] = s * 0.125f - mean * mean;
    }
    __syncthreads();
#pragma unroll
    for (int cc = 0; cc < kC / 2; ++cc) {
      const int c = ph * (kC / 2) + cc;
      out[outBase + ((size_t)c * kNPlanes + (dHalf * kDTile + dd2)) * kNPix
          + pG * kPTile + pp2] = sT[cc][pp2][dd2];
    }
  }
}

extern "C" void kernel_launch(void* const* d_in, const int* in_sizes, int n_in,
                              void* d_out, int out_size, void* d_ws, size_t ws_size,
                              hipStream_t stream) {
  const float* feats  = (const float*)d_in[0];
  const float* rot    = (const float*)d_in[1];
  const float* tv     = (const float*)d_in[2];
  const float* Kmat   = (const float*)d_in[3];
  const int*   edges  = (const int*)d_in[4];
  float* out = (float*)d_out;

  const size_t featsTBytes = (size_t)kNImgs * kFeatPix * kC * sizeof(_Float16);  // 5.4 MB
  const int gridMain = kNImgs * kBlocksPerRef;     // 7056 blocks of 256 threads

  if (ws_size >= featsTBytes) {
    _Float16* featsT = (_Float16*)d_ws;
    const int nT = kNImgs * kFeatPerImg;           // 2,709,504
    transpose_feats_kernel<<<(nT + 255) / 256, 256, 0, stream>>>(feats, featsT);
    psv_var_kernel<true><<<gridMain, 256, 0, stream>>>(feats, featsT, rot, tv, Kmat, edges, out);
  } else {
    psv_var_kernel<false><<<gridMain, 256, 0, stream>>>(feats, nullptr, rot, tv, Kmat, edges, out);
  }
}

// Round 12
// 150.175 us; speedup vs baseline: 1.0311x; 1.0311x over previous
//
#include <hip/hip_runtime.h>

// ---- static config (matches reference) ----
constexpr int kNImgs   = 9;
constexpr int kC       = 24;
constexpr int kHF      = 112, kWF = 112;
constexpr int kHD      = 56,  kWD = 56;
constexpr int kNPix    = kHD * kWD;              // 3136
constexpr int kNPlanes = 64;
constexpr int kPtsPerRef = kNPlanes * kNPix;     // 200704
constexpr int kEdgesPerRef = 8;
constexpr int kNEdges  = kNImgs * kEdgesPerRef;  // 72
constexpr int kFeatPix = kHF * kWF;              // 12544
constexpr int kFeatPerImg = kC * kFeatPix;       // 301056

// block geometry: 256 threads = 32 d (lane-major) x 8 p
constexpr int kDTile = 32, kPTile = 8;
constexpr int kDHalves = kNPlanes / kDTile;        // 2
constexpr int kPGroups = kNPix / kPTile;           // 392
constexpr int kBlocksPerRef = kDHalves * kPGroups; // 784

typedef _Float16 half8  __attribute__((ext_vector_type(8)));
typedef _Float16 half2v __attribute__((ext_vector_type(2)));
typedef float    float2v __attribute__((ext_vector_type(2)));
typedef unsigned int uint4v __attribute__((ext_vector_type(4)));

__device__ inline half2v u2h(unsigned int u) {
  union { unsigned int u; half2v h; } cv; cv.u = u; return cv.h;
}

#if __has_builtin(__builtin_amdgcn_rcpf)
__device__ inline float fastrcp(float x) { return __builtin_amdgcn_rcpf(x); }
#else
__device__ inline float fastrcp(float x) { return 1.0f / x; }
#endif

// ---------- small 3x3 helpers ----------
__device__ inline void mm3(const float* A, const float* B, float* C) {
#pragma unroll
  for (int i = 0; i < 3; ++i)
#pragma unroll
    for (int j = 0; j < 3; ++j)
      C[i*3+j] = A[i*3+0]*B[0*3+j] + A[i*3+1]*B[1*3+j] + A[i*3+2]*B[2*3+j];
}

__device__ inline void inv3(const float* A, float* I) {
  float a=A[0],b=A[1],c=A[2],d=A[3],e=A[4],f=A[5],g=A[6],h=A[7],i=A[8];
  float c00 = e*i - f*h;
  float c01 = -(d*i - f*g);
  float c02 = d*h - e*g;
  float det = a*c00 + b*c01 + c*c02;
  float r = 1.0f / det;
  I[0] = c00*r;           I[1] = (c*h - b*i)*r;  I[2] = (b*f - c*e)*r;
  I[3] = c01*r;           I[4] = (a*i - c*g)*r;  I[5] = (c*d - a*f)*r;
  I[6] = c02*r;           I[7] = (b*g - a*h)*r;  I[8] = (a*e - b*d)*r;
}

// ---------- transpose+convert feats [N,C,HF,WF] f32 -> [N,HF,WF,C] f16 ----------
__global__ __launch_bounds__(256)
void transpose_feats_kernel(const float* __restrict__ f, _Float16* __restrict__ ft) {
  int idx = blockIdx.x * 256 + threadIdx.x;
  if (idx >= kNImgs * kFeatPerImg) return;
  int n  = idx / kFeatPerImg;
  int r  = idx - n * kFeatPerImg;
  int c  = r / kFeatPix;
  int yx = r - c * kFeatPix;
  ft[((size_t)n * kFeatPix + yx) * kC + c] = (_Float16)f[idx];
}

// ---------- main fused kernel ----------
// block = (ref n, d-half, p-group); lanes d-major (wave = 32 d x 2 p) so a
// wave's gathers walk an epipolar segment (sub-pixel step -> line sharing).
// Inner loop: v_pk_fma_f16 over natural channel pairs, f32 edge accumulation.
// Constraints learned: VGPR <= 64 (R9/R11: cliff halves occupancy; the 48-reg
// accumulator means NO cross-edge duplication), plain loop only (R8: manual
// pipelines spill), stride-36 sT (R11: zero bank conflicts).
template <bool TR>
__global__ __launch_bounds__(256)
void psv_var_kernel(const float* __restrict__ feats,      // [N,C,HF,WF] f32 (!TR)
                    const _Float16* __restrict__ featsT,  // [N,HF,WF,C] f16 (TR)
                    const float* __restrict__ rotmats,    // [N,3,3]
                    const float* __restrict__ tvecs,      // [N,3]
                    const float* __restrict__ Kmat,       // [N,3,3]
                    const int*   __restrict__ edges,      // [2,72]
                    float* __restrict__ out) {            // [N,C,D,HD,WD]
  __shared__ float sM[kEdgesPerRef][9];
  __shared__ float sB[kEdgesPerRef][3];
  __shared__ int   sSrc[kEdgesPerRef];
  __shared__ int   sUIdx[kEdgesPerRef];
  __shared__ float sMult[kEdgesPerRef];
  __shared__ int   sKU;
  // stride 36: write bank=(4*psub+dsub)%32, read bank=(4*pp2+dd2)%32 —
  // both <=2 lanes/bank (free; verified 0 conflicts in R11).
  __shared__ float sT[kC / 2][kPTile][kDTile + 4];

  // bijective XCD-chunk swizzle (m204 formula; works for any gridDim)
  const int nwg = gridDim.x;
  const int orig = blockIdx.x;
  const int q = nwg >> 3, r8 = nwg & 7;
  const int xcd = orig & 7, lin = orig >> 3;
  const int bid = ((xcd < r8) ? xcd * (q + 1) : r8 * (q + 1) + (xcd - r8) * q) + lin;

  const int n     = bid / kBlocksPerRef;
  const int rem   = bid - n * kBlocksPerRef;
  const int dHalf = rem / kPGroups;
  const int pG    = rem - dHalf * kPGroups;

  const int t = threadIdx.x;

  if (t < kEdgesPerRef) {
    const int e  = n * kEdgesPerRef + t;
    const int re = edges[e];            // ref row
    const int se = edges[kNEdges + e];  // src row
    sSrc[t] = se;

    const float* Rr = rotmats + re * 9;
    const float* Rs = rotmats + se * 9;
    const float* Kr = Kmat + re * 9;
    const float* Ks = Kmat + se * 9;
    const float* tr = tvecs + re * 3;
    const float* ts = tvecs + se * 3;

    float RrT[9];
#pragma unroll
    for (int i = 0; i < 3; ++i)
#pragma unroll
      for (int j = 0; j < 3; ++j) RrT[i*3+j] = Rr[j*3+i];

    float Kinv[9], A[9], T1[9], M[9];
    inv3(Kr, Kinv);
    mm3(Rs, RrT, A);       // A = R_src * R_ref^T
    mm3(A, Kinv, T1);
    mm3(Ks, T1, M);        // M = K_src * A * K_ref^-1

    float At0 = A[0]*tr[0] + A[1]*tr[1] + A[2]*tr[2];
    float At1 = A[3]*tr[0] + A[4]*tr[1] + A[5]*tr[2];
    float At2 = A[6]*tr[0] + A[7]*tr[1] + A[8]*tr[2];
    float bv0 = ts[0] - At0, bv1 = ts[1] - At1, bv2 = ts[2] - At2;
#pragma unroll
    for (int i = 0; i < 9; ++i) sM[t][i] = M[i];
#pragma unroll
    for (int i = 0; i < 3; ++i)
      sB[t][i] = Ks[i*3+0]*bv0 + Ks[i*3+1]*bv1 + Ks[i*3+2]*bv2;
  }
  __syncthreads();

  if (t == 0) {
    int k = 0;
    for (int j = 0; j < kEdgesPerRef; ++j) {
      const int s = sSrc[j];
      bool dup = false;
      for (int i = 0; i < k; ++i) {
        if (sSrc[sUIdx[i]] == s) { sMult[i] += 1.0f; dup = true; break; }
      }
      if (!dup) { sUIdx[k] = j; sMult[k] = 1.0f; ++k; }
    }
    sKU = k;
  }
  __syncthreads();

  // d-major lane mapping
  const int dsub = t & 31;
  const int psub = t >> 5;
  const int d = dHalf * kDTile + dsub;
  const int p = pG * kPTile + psub;
  const int h = p / kWD;
  const int w = p - h * kWD;

  const float u = (float)w * (447.0f / 55.0f);   // linspace(0,447,56)
  const float v = (float)h * (447.0f / 55.0f);
  const float depth = 0.5f + 0.05f * (float)d;

  float2v acc2[kC / 2], accsq2[kC / 2];
#pragma unroll
  for (int i = 0; i < kC / 2; ++i) {
    acc2[i] = (float2v){0.0f, 0.0f};
    accsq2[i] = (float2v){0.0f, 0.0f};
  }

  const int kU = sKU;

  for (int jj = 0; jj < kU; ++jj) {
    const int j = sUIdx[jj];
    const float mult = sMult[jj];
    const float* M = sM[j];
    const float px = depth * (M[0]*u + M[1]*v + M[2]) + sB[j][0];
    const float py = depth * (M[3]*u + M[4]*v + M[5]) + sB[j][1];
    const float pz = depth * (M[6]*u + M[7]*v + M[8]) + sB[j][2];
    const float rz = fastrcp(fabsf(pz) + 1e-8f);

    const float x = px * rz * (111.0f / 447.0f);
    const float y = py * rz * (111.0f / 447.0f);

    const float x0 = floorf(x), y0 = floorf(y);
    const float wx = x - x0, wy = y - y0;
    const bool vx0 = (x0 >= 0.0f)  && (x0 <= 111.0f);
    const bool vx1 = (x0 >= -1.0f) && (x0 <= 110.0f);
    const bool vy0 = (y0 >= 0.0f)  && (y0 <= 111.0f);
    const bool vy1 = (y0 >= -1.0f) && (y0 <= 110.0f);
    const float w00 = (vx0 && vy0) ? (1.0f - wx) * (1.0f - wy) : 0.0f;
    const float w01 = (vx1 && vy0) ? wx * (1.0f - wy) : 0.0f;
    const float w10 = (vx0 && vy1) ? (1.0f - wx) * wy : 0.0f;
    const float w11 = (vx1 && vy1) ? wx * wy : 0.0f;

    const int xc0 = (int)fminf(fmaxf(x0,        0.0f), 111.0f);
    const int xc1 = (int)fminf(fmaxf(x0 + 1.0f, 0.0f), 111.0f);
    const int yc0 = (int)fminf(fmaxf(y0,        0.0f), 111.0f);
    const int yc1 = (int)fminf(fmaxf(y0 + 1.0f, 0.0f), 111.0f);

    const int src = sSrc[j];
    if constexpr (TR) {
      // broadcast f16 weight pairs; taps accumulate via v_pk_fma_f16 on
      // natural channel pairs (32-bit sub-registers of the 16B loads).
      const _Float16 h00 = (_Float16)w00, h01 = (_Float16)w01;
      const _Float16 h10 = (_Float16)w10, h11 = (_Float16)w11;
      const half2v w00p = {h00, h00}, w01p = {h01, h01};
      const half2v w10p = {h10, h10}, w11p = {h11, h11};
      const float2v mult2 = {mult, mult};
      const _Float16* base = featsT + (size_t)src * kFeatPix * kC;
      const int o00 = (yc0 * kWF + xc0) * kC;
      const int o01 = (yc0 * kWF + xc1) * kC;
      const int o10 = (yc1 * kWF + xc0) * kC;
      const int o11 = (yc1 * kWF + xc1) * kC;
#pragma unroll
      for (int i = 0; i < kC / 8; ++i) {          // 3 chunks of 8 f16 channels
        const uint4v q00 = *(const uint4v*)(base + o00 + 8*i);
        const uint4v q01 = *(const uint4v*)(base + o01 + 8*i);
        const uint4v q10 = *(const uint4v*)(base + o10 + 8*i);
        const uint4v q11 = *(const uint4v*)(base + o11 + 8*i);
#pragma unroll
        for (int k2 = 0; k2 < 4; ++k2) {          // 2-channel sub-vectors
          const half2v val2h = u2h(q00[k2]) * w00p + u2h(q01[k2]) * w01p
                             + u2h(q10[k2]) * w10p + u2h(q11[k2]) * w11p;
          const float2v val2 = {(float)val2h[0], (float)val2h[1]};
          const float2v mval2 = mult2 * val2;
          const int idx = i*4 + k2;
          acc2[idx] += mval2;
          accsq2[idx] = mval2 * val2 + accsq2[idx];
        }
      }
    } else {
      const float* base = feats + (size_t)src * kFeatPerImg;
      const int o00 = yc0 * kWF + xc0;
      const int o01 = yc0 * kWF + xc1;
      const int o10 = yc1 * kWF + xc0;
      const int o11 = yc1 * kWF + xc1;
#pragma unroll
      for (int i = 0; i < kC / 2; ++i) {
#pragma unroll
        for (int kk = 0; kk < 2; ++kk) {
          const int c = 2*i + kk;
          const float* bc = base + (size_t)c * kFeatPix;
          float val = w00*bc[o00] + w01*bc[o01] + w10*bc[o10] + w11*bc[o11];
          const float mval = mult * val;
          acc2[i][kk] += mval;
          accsq2[i][kk] = __builtin_fmaf(mval, val, accsq2[i][kk]);
        }
      }
    }
  }

  // ---- epilogue: LDS transpose (d-major lanes -> p-coalesced stores) ----
  // two phases of 12 channels; 2 barriers each.
  const int pp2 = t & (kPTile - 1);   // store-side pixel index (0..7)
  const int dd2 = t >> 3;             // store-side depth index (0..31)
  const size_t outBase = (size_t)n * kC * (size_t)kPtsPerRef;
#pragma unroll
  for (int ph = 0; ph < 2; ++ph) {
    __syncthreads();               // protect previous phase's reads
#pragma unroll
    for (int cc = 0; cc < kC / 2; ++cc) {
      const int c = ph * (kC / 2) + cc;
      const float a = acc2[c >> 1][c & 1];
      const float s = accsq2[c >> 1][c & 1];
      const float mean = a * 0.125f;
      sT[cc][psub][dsub] = s * 0.125f - mean * mean;
    }
    __syncthreads();
#pragma unroll
    for (int cc = 0; cc < kC / 2; ++cc) {
      const int c = ph * (kC / 2) + cc;
      out[outBase + ((size_t)c * kNPlanes + (dHalf * kDTile + dd2)) * kNPix
          + pG * kPTile + pp2] = sT[cc][pp2][dd2];
    }
  }
}

extern "C" void kernel_launch(void* const* d_in, const int* in_sizes, int n_in,
                              void* d_out, int out_size, void* d_ws, size_t ws_size,
                              hipStream_t stream) {
  const float* feats  = (const float*)d_in[0];
  const float* rot    = (const float*)d_in[1];
  const float* tv     = (const float*)d_in[2];
  const float* Kmat   = (const float*)d_in[3];
  const int*   edges  = (const int*)d_in[4];
  float* out = (float*)d_out;

  const size_t featsTBytes = (size_t)kNImgs * kFeatPix * kC * sizeof(_Float16);  // 5.4 MB
  const int gridMain = kNImgs * kBlocksPerRef;     // 7056 blocks of 256 threads

  if (ws_size >= featsTBytes) {
    _Float16* featsT = (_Float16*)d_ws;
    const int nT = kNImgs * kFeatPerImg;           // 2,709,504
    transpose_feats_kernel<<<(nT + 255) / 256, 256, 0, stream>>>(feats, featsT);
    psv_var_kernel<true><<<gridMain, 256, 0, stream>>>(feats, featsT, rot, tv, Kmat, edges, out);
  } else {
    psv_var_kernel<false><<<gridMain, 256, 0, stream>>>(feats, nullptr, rot, tv, Kmat, edges, out);
  }
}